// Round 13
// baseline (171.644 us; speedup 1.0000x reference)
//
#include <hip/hip_runtime.h>

// CrossAttentionPro on MI355X — Round 25 (R24 resubmit; prior run died to
// container-acquisition failure, kernel never executed; code re-audited):
//  Straggler parallelism (flash untouched at proven R23 form):
//   - wtq2: 512 blocks (t-chunks of 64) = 2 blocks/CU (was 256 = 1/CU,
//     latency-bound 16-iter pipeline with zero TLP). Phase-1 WT redundancy
//     32x/z (trivial 8.4 MFLOP/block); XCD remap keeps panel reads L2-hot.
//   - proj: BN=32 -> grid 16x64 = 1024 blocks (4/CU), XCD remap, NLD==3
//     counted-vmcnt branch. Per-element math bit-identical.
//  Kept: R23 flash (64-s tiles, 1536 blocks, launch_bounds(256,4) natural
//  regalloc, R19 rhythm: 3 barriers/tile, K dbuf, counted vmcnt(2),
//  separated no-max exp2 softmax, ones-MFMA row-sum, pkrtz+permlane P-frag
//  butterfly, setprio), swapped-operand S^T=mfma(K,Q), coalesced qkv
//  epilogue via LDS slab, f16 PO slabs + 6-slab combine, bit-packed mask,
//  XCD z-locality, XCD-chunked GEMM remaps.

typedef _Float16 half_t;
typedef _Float16 half8 __attribute__((ext_vector_type(8)));
typedef _Float16 half4v __attribute__((ext_vector_type(4)));
typedef float floatx4 __attribute__((ext_vector_type(4)));
typedef int int4v __attribute__((ext_vector_type(4)));

constexpr int Bc = 2, Tc = 2048, Mc = 1024, Cc = 512, Hc = 8, Dc = 64;
constexpr long BTC = (long)Bc * Tc * Cc;
constexpr long ZT  = (long)Bc * Hc * Tc;
constexpr float S1 = 0.18033688f;                 // 0.125 * log2(e)

enum { EPI_F16STORE = 0, EPI_QKV_XY = 1, EPI_PROJ = 2 };

struct EpiParams {
  half_t* h0;        // QXs  / f16 dest
  half_t* h1;        // KX
  half_t* h2;        // VXT
  half_t* h3;        // QYT
  half_t* h4;        // KY
  half_t* h5;        // KYT
  half_t* h6;        // VYT
  float* f0;
  const float* bias;
  float scale;
  int ldc;
  long bstride;
};

// async global->LDS, 16B per lane; dst must be wave-uniform base + lane*16.
__device__ __forceinline__ void gld_lds16(const half_t* g, half_t* l) {
  __builtin_amdgcn_global_load_lds(
      (const __attribute__((address_space(1))) void*)g,
      (__attribute__((address_space(3))) void*)l, 16, 0, 0);
}

// pack 2 f32 -> 2 f16 (RTZ) as one u32
__device__ __forceinline__ int pkrtz(float a, float b) {
  return __builtin_bit_cast(int, __builtin_amdgcn_cvt_pkrtz(a, b));
}
// v_permlane16_swap: a.row1<->b.row0, a.row3<->b.row2 (rows = 16-lane groups)
__device__ __forceinline__ void pl16(int& a, int& b) {
  asm volatile("v_permlane16_swap_b32 %0, %1" : "+v"(a), "+v"(b));
}
// v_permlane32_swap: a.rows{2,3} <-> b.rows{0,1}
__device__ __forceinline__ void pl32(int& a, int& b) {
  asm volatile("v_permlane32_swap_b32 %0, %1" : "+v"(a), "+v"(b));
}

// ---------------------------------------------------------------- GEMM (NT)
// C[r,c] = sum_k A[r,k]*Bt[c,k]. BK=64 double-buffered async staging with
// counted vmcnt, swizzled chunks (conflict-free ds_read_b128).
// GX/GY: logical grid dims for XCD-chunked remap (0 = no remap).
template <int BM, int BN, int WMG, int WNG, int EPI, int GX = 0, int GY = 0>
__global__ __launch_bounds__(256) void gemm_nt(
    const half_t* __restrict__ A, const half_t* __restrict__ Bt,
    int K, int lda, int ldb, long bsA, long bsB, EpiParams ep)
{
  constexpr int BK = 64;
  constexpr int WTM = BM / WMG, WTN = BN / WNG;
  constexpr int MI = WTM / 16, NI = WTN / 16;
  constexpr int AIT = BM * BK / 8 / 256;
  constexpr int BIT = BN * BK / 8 / 256;
  constexpr int NLD = AIT + BIT;
  __shared__ __align__(16) half_t As[2][BM * BK];
  __shared__ __align__(16) half_t Bs[2][BN * BK];

  const int tid = threadIdx.x;
  const int lane = tid & 63;
  const int wave = tid >> 6;
  const int wm = wave / WNG, wn = wave % WNG;
  const int r16 = lane & 15, g = lane >> 4;
  const int z = blockIdx.z;

  int bxl = blockIdx.x, byl = blockIdx.y;
  if constexpr (GX > 0) {
    constexpr int CHUNK = GX * GY / 8;   // GX*GY % 8 == 0 required
    const int f = byl * GX + bxl;
    const int L = (f & 7) * CHUNK + (f >> 3);
    bxl = L % GX; byl = L / GX;
  }
  const long m0 = (long)byl * BM;
  const long n0 = (long)bxl * BN;
  const half_t* Abase = A + (long)z * bsA + m0 * (long)lda;
  const half_t* Bbase = Bt + (long)z * bsB + n0 * (long)ldb;

  const int rA = wm * WTM + r16;
  const int rB = wn * WTN + r16;

  floatx4 acc[MI][NI];
#pragma unroll
  for (int mi = 0; mi < MI; ++mi)
#pragma unroll
    for (int ni = 0; ni < NI; ++ni)
      acc[mi][ni] = floatx4{0.f, 0.f, 0.f, 0.f};

  auto stage = [&](int kt, int buf) {
#pragma unroll
    for (int i = 0; i < AIT; ++i) {
      const int c = tid + i * 256;
      const int row = c >> 3, js = c & 7;
      const int jg = js ^ (row & 7);
      gld_lds16(Abase + (long)row * lda + kt + jg * 8, &As[buf][c * 8]);
    }
#pragma unroll
    for (int i = 0; i < BIT; ++i) {
      const int c = tid + i * 256;
      const int row = c >> 3, js = c & 7;
      const int jg = js ^ (row & 7);
      gld_lds16(Bbase + (long)row * ldb + kt + jg * 8, &Bs[buf][c * 8]);
    }
  };

  const int NIT = K / BK;
  stage(0, 0);
  asm volatile("" ::: "memory");

  for (int it = 0; it < NIT; ++it) {
    const bool hn = (it + 1 < NIT);
    if (hn) stage((it + 1) * BK, (it + 1) & 1);
    asm volatile("" ::: "memory");
    if (hn) {
      if constexpr (NLD == 6) asm volatile("s_waitcnt vmcnt(6)" ::: "memory");
      else if constexpr (NLD == 4) asm volatile("s_waitcnt vmcnt(4)" ::: "memory");
      else if constexpr (NLD == 3) asm volatile("s_waitcnt vmcnt(3)" ::: "memory");
      else if constexpr (NLD == 8) asm volatile("s_waitcnt vmcnt(8)" ::: "memory");
      else asm volatile("s_waitcnt vmcnt(0)" ::: "memory");
    } else {
      asm volatile("s_waitcnt vmcnt(0)" ::: "memory");
    }
    __builtin_amdgcn_s_barrier();
    asm volatile("" ::: "memory");

    const half_t* Ab = As[it & 1];
    const half_t* Bb = Bs[it & 1];
    half8 aF[MI][2], bF[NI][2];
#pragma unroll
    for (int mi = 0; mi < MI; ++mi)
#pragma unroll
      for (int k2 = 0; k2 < 2; ++k2)
        aF[mi][k2] = *reinterpret_cast<const half8*>(
            &Ab[(rA + mi * 16) * BK + ((k2 * 4 + g) ^ (r16 & 7)) * 8]);
#pragma unroll
    for (int ni = 0; ni < NI; ++ni)
#pragma unroll
      for (int k2 = 0; k2 < 2; ++k2)
        bF[ni][k2] = *reinterpret_cast<const half8*>(
            &Bb[(rB + ni * 16) * BK + ((k2 * 4 + g) ^ (r16 & 7)) * 8]);
    __builtin_amdgcn_s_setprio(1);
#pragma unroll
    for (int k2 = 0; k2 < 2; ++k2)
#pragma unroll
      for (int mi = 0; mi < MI; ++mi)
#pragma unroll
        for (int ni = 0; ni < NI; ++ni)
          acc[mi][ni] = __builtin_amdgcn_mfma_f32_16x16x32_f16(
              aF[mi][k2], bF[ni][k2], acc[mi][ni], 0, 0, 0);
    __builtin_amdgcn_s_setprio(0);
    asm volatile("s_waitcnt lgkmcnt(0)" ::: "memory");
    __builtin_amdgcn_s_barrier();
    asm volatile("" ::: "memory");
  }

  // epilogue: C/D layout col=lane&15, row=(lane>>4)*4+reg  [m89-verified]
  // transposed-output slab (reuses As, free after last barrier): [64][136]
  half_t* Txp = &As[0][0];
  const bool isx  = (m0 < (long)Bc * Tc);
  const int which = (int)(n0 >> 9);
  const int hh    = ((int)n0 & 511) >> 6;

#pragma unroll
  for (int mi = 0; mi < MI; ++mi) {
#pragma unroll
    for (int ni = 0; ni < NI; ++ni) {
#pragma unroll
      for (int reg = 0; reg < 4; ++reg) {
        const int r = (int)m0 + wm * WTM + mi * 16 + g * 4 + reg;
        const int c = (int)n0 + wn * WTN + ni * 16 + r16;
        const float v = acc[mi][ni][reg];
        if constexpr (EPI == EPI_F16STORE) {
          ep.h0[(long)z * ep.bstride + (long)r * ep.ldc + c] = (half_t)(v * ep.scale);
        } else if constexpr (EPI == EPI_QKV_XY) {
          const float val = v + ep.bias[c];
          const int d = c & 63;
          const int rloc = r - (int)m0;
          if (isx) {                    // x rows
            const int b = (int)(m0 >> 11);
            const int t = r & (Tc - 1);
            const long bh = (long)(b * Hc + hh);
            if (which == 0)      ep.h0[(bh * Tc + t) * Dc + d] = (half_t)(val * S1);  // QXs
            else if (which == 1) ep.h1[(bh * Tc + t) * Dc + d] = (half_t)val;         // KX
            else                 Txp[d * 136 + rloc] = (half_t)val;                   // VXT (LDS)
          } else {                      // y rows
            const long m2 = m0 - (long)Bc * Tc;
            const int b = (int)(m2 >> 10);
            const int t = (r - Bc * Tc) & (Mc - 1);
            const long bh = (long)(b * Hc + hh);
            if (which == 0)      Txp[d * 136 + rloc] = (half_t)(val * 0.125f);        // QYT (LDS)
            else if (which == 1) { ep.h4[(bh * Mc + t) * Dc + d] = (half_t)val;       // KY
                                   Txp[d * 136 + rloc] = (half_t)val; }               // KYT (LDS)
            else                 Txp[d * 136 + rloc] = (half_t)val;                   // VYT (LDS)
          }
        } else {  // EPI_PROJ
          ep.f0[(long)r * Cc + c] = v + ep.bias[c];
        }
      }
    }
  }

  if constexpr (EPI == EPI_QKV_XY && BM == 128) {
    const bool hasT = isx ? (which == 2) : true;
    if (hasT) {                     // block-uniform -> barrier is safe
      __syncthreads();
      half_t* dstT; int L; long tb; int b;
      if (isx) { dstT = ep.h2; L = Tc; tb = m0 & (Tc - 1); b = (int)(m0 >> 11); }
      else {
        const long m2 = m0 - (long)Bc * Tc;
        b = (int)(m2 >> 10); tb = m2 & (Mc - 1); L = Mc;
        dstT = (which == 0) ? ep.h3 : (which == 1) ? ep.h5 : ep.h6;
      }
      const long bh = (long)(b * Hc + hh);
      const int dr = tid >> 2, qd = tid & 3;       // 64 rows x 4 quarters
      half_t* gbase = dstT + (bh * 64 + dr) * L + tb + qd * 32;
#pragma unroll
      for (int j = 0; j < 4; ++j) {
        const half8 v8 = *reinterpret_cast<const half8*>(&Txp[dr * 136 + qd * 32 + j * 8]);
        *reinterpret_cast<half8*>(&gbase[j * 8]) = v8;
      }
    }
  }
}

// --------------------------------------------- fused WT+Q2 kernel
// grid 512 flat (2 blocks/CU); logical (t-chunk of 64, z) via XCD-chunked
// remap (same-z blocks co-locate -> QYT/KYT panel reads L2-hot).
// Phase 1: WT[64][64] = 0.125 * QYTs[z] KYT[z]^T (K=1024, pipelined dbuf)
// -> LDS in phase-2 fragment layout (computed redundantly per t-chunk).
// Phase 2: Q2[z, t0..t0+63, :] = QXs * WT^T (K=64, MI=1: 16 rows/wave).
__global__ __launch_bounds__(256) void wtq2(
    const half_t* __restrict__ QYT, const half_t* __restrict__ KYT,
    const half_t* __restrict__ QX, half_t* __restrict__ Q2)
{
  __shared__ __align__(16) half_t As[2][4096];
  __shared__ __align__(16) half_t Bs[2][4096];
  __shared__ __align__(16) half_t WTs[4096];
  const int tid = threadIdx.x, lane = tid & 63, wave = tid >> 6;
  const int wm = wave >> 1, wn = wave & 1;
  const int r16 = lane & 15, g = lane >> 4;
  const int f = blockIdx.x;
  const int L = (f & 7) * 64 + (f >> 3);   // 512 blocks, chunk=64
  const int z = L >> 5;                    // 32 t-chunks per z
  const int t0 = (L & 31) * 64;
  const half_t* Aq = QYT + (long)z * Dc * Mc;
  const half_t* Bk = KYT + (long)z * Dc * Mc;

  auto stage1 = [&](int kt, int buf) {
#pragma unroll
    for (int i = 0; i < 2; ++i) {
      const int c = tid + i * 256;
      const int row = c >> 3, js = c & 7, jg = js ^ (row & 7);
      gld_lds16(Aq + (long)row * Mc + kt + jg * 8, &As[buf][c * 8]);
    }
#pragma unroll
    for (int i = 0; i < 2; ++i) {
      const int c = tid + i * 256;
      const int row = c >> 3, js = c & 7, jg = js ^ (row & 7);
      gld_lds16(Bk + (long)row * Mc + kt + jg * 8, &Bs[buf][c * 8]);
    }
  };

  floatx4 acc[2][2];
#pragma unroll
  for (int mi = 0; mi < 2; ++mi)
#pragma unroll
    for (int ni = 0; ni < 2; ++ni) acc[mi][ni] = floatx4{0.f, 0.f, 0.f, 0.f};

  const int rA = wm * 32 + r16, rB = wn * 32 + r16;
  stage1(0, 0);
  asm volatile("" ::: "memory");
  for (int it = 0; it < 16; ++it) {
    const bool hn = (it < 15);
    if (hn) stage1((it + 1) * 64, (it + 1) & 1);
    asm volatile("" ::: "memory");
    if (hn) asm volatile("s_waitcnt vmcnt(4)" ::: "memory");
    else    asm volatile("s_waitcnt vmcnt(0)" ::: "memory");
    __builtin_amdgcn_s_barrier();
    asm volatile("" ::: "memory");
    const half_t* Ab = As[it & 1];
    const half_t* Bb = Bs[it & 1];
    half8 aF[2][2], bF[2][2];
#pragma unroll
    for (int mi = 0; mi < 2; ++mi)
#pragma unroll
      for (int k2 = 0; k2 < 2; ++k2)
        aF[mi][k2] = *reinterpret_cast<const half8*>(
            &Ab[(rA + mi * 16) * 64 + ((k2 * 4 + g) ^ (r16 & 7)) * 8]);
#pragma unroll
    for (int ni = 0; ni < 2; ++ni)
#pragma unroll
      for (int k2 = 0; k2 < 2; ++k2)
        bF[ni][k2] = *reinterpret_cast<const half8*>(
            &Bb[(rB + ni * 16) * 64 + ((k2 * 4 + g) ^ (r16 & 7)) * 8]);
    __builtin_amdgcn_s_setprio(1);
#pragma unroll
    for (int k2 = 0; k2 < 2; ++k2)
#pragma unroll
      for (int mi = 0; mi < 2; ++mi)
#pragma unroll
        for (int ni = 0; ni < 2; ++ni)
          acc[mi][ni] = __builtin_amdgcn_mfma_f32_16x16x32_f16(
              aF[mi][k2], bF[ni][k2], acc[mi][ni], 0, 0, 0);
    __builtin_amdgcn_s_setprio(0);
    asm volatile("s_waitcnt lgkmcnt(0)" ::: "memory");
    __builtin_amdgcn_s_barrier();
    asm volatile("" ::: "memory");
  }

  // phase-2 A stage (As fully free after final barrier): QX rows t0..t0+63
  half_t* P2 = &As[0][0];
#pragma unroll
  for (int i = 0; i < 2; ++i) {
    const int c = tid + i * 256;
    const int row = c >> 3, js = c & 7, jg = js ^ (row & 7);
    gld_lds16(QX + ((long)z * Tc + t0 + row) * 64 + jg * 8, P2 + c * 8);
  }
  // WT -> LDS f16 in phase-2 fragment layout (chunk swizzle js^(row&7))
#pragma unroll
  for (int mi = 0; mi < 2; ++mi)
#pragma unroll
    for (int ni = 0; ni < 2; ++ni)
#pragma unroll
      for (int reg = 0; reg < 4; ++reg) {
        const int r = wm * 32 + mi * 16 + g * 4 + reg;   // d2
        const int c = wn * 32 + ni * 16 + r16;           // d1
        WTs[r * 64 + (((c >> 3) ^ (r & 7)) << 3) + (c & 7)] =
            (half_t)(acc[mi][ni][reg] * 0.125f);
      }
  __syncthreads();   // drains vmcnt (QX stage) + lgkm (WTs writes)

  // phase 2: per wave 16 t-rows (MI=1), full 64 d2 cols, K=64
  floatx4 a2[4];
#pragma unroll
  for (int ni = 0; ni < 4; ++ni) a2[ni] = floatx4{0.f, 0.f, 0.f, 0.f};
  const int rA2 = wave * 16 + r16;
  half8 aF2[2], bF2[4][2];
#pragma unroll
  for (int k2 = 0; k2 < 2; ++k2)
    aF2[k2] = *reinterpret_cast<const half8*>(
        &P2[rA2 * 64 + ((k2 * 4 + g) ^ (r16 & 7)) * 8]);
#pragma unroll
  for (int ni = 0; ni < 4; ++ni)
#pragma unroll
    for (int k2 = 0; k2 < 2; ++k2)
      bF2[ni][k2] = *reinterpret_cast<const half8*>(
          &WTs[(ni * 16 + r16) * 64 + ((k2 * 4 + g) ^ (r16 & 7)) * 8]);
#pragma unroll
  for (int k2 = 0; k2 < 2; ++k2)
#pragma unroll
    for (int ni = 0; ni < 4; ++ni)
      a2[ni] = __builtin_amdgcn_mfma_f32_16x16x32_f16(
          aF2[k2], bF2[ni][k2], a2[ni], 0, 0, 0);
#pragma unroll
  for (int ni = 0; ni < 4; ++ni)
#pragma unroll
    for (int reg = 0; reg < 4; ++reg) {
      const int t = t0 + wave * 16 + g * 4 + reg;
      const int c = ni * 16 + r16;
      Q2[((long)z * Tc + t) * 64 + c] = (half_t)a2[ni][reg];
    }
}

// ------------------------------------------------------------ flash staging
// s-tile 64: K tile [64 s][64 d] = 8KB, V^T tile [64 d][64 s] = 8KB.
// 2 gld_lds16 per thread each (counted vmcnt relies on this).
__device__ __forceinline__ void stageK64(const half_t* Kz, int s0, half_t* dst, int tid) {
#pragma unroll
  for (int i = 0; i < 2; ++i) {
    const int c = tid + i * 256;
    const int row = c >> 3, js = c & 7;
    const int jg = js ^ (row & 7);
    gld_lds16(Kz + (long)(s0 + row) * 64 + jg * 8, dst + c * 8);
  }
}
__device__ __forceinline__ void stageV64(const half_t* Vz, int s0, int Slen, half_t* dst, int tid) {
#pragma unroll
  for (int i = 0; i < 2; ++i) {
    const int c = tid + i * 256;
    const int row = c >> 3, js = c & 7;
    const int jg = js ^ (row & 7);
    gld_lds16(Vz + (long)row * Slen + s0 + jg * 8, dst + c * 8);
  }
}

// --------------------------------------------------------- flash body (MI=2)
// 128 q-rows/block, 8 s-tiles of 64 over [sbeg, sbeg+512). R19 rhythm:
//  vmcnt(2)+barrier [K(t) ready] ; QK MFMA cluster ; issue K(t+1) ; softmax
//  (mask+exp2) ; vmcnt(2)+barrier [V(t) ready] ; PV (+ones-MFMA row-sum) ;
//  barrier ; issue V(t+1). Always partial: unnormalized O f16 + row-sum L.
// lds layout (24KB): Kb0 = lds[0..4096), Kb1 = [4096..8192), Vb = [8192..12288)
template <bool MASKED>
__device__ __forceinline__ void flash_body(
    const half_t* __restrict__ Qp, const half_t* __restrict__ Kp,
    const half_t* __restrict__ Vp, const unsigned char* __restrict__ mpk,
    half_t* __restrict__ POh, float* __restrict__ Lp,
    int Slen, int sbeg, int z, int q0, half_t* lds)
{
  const int tid = threadIdx.x, lane = tid & 63, w = tid >> 6;
  const int r16 = lane & 15, g = lane >> 4;
  const int b = z >> 3, h = z & 7;
  const int NT = Slen >> 7;                 // 128-tile count (mask indexing)
  const half_t* Qz = Qp + ((long)z * Tc + q0) * 64;
  const half_t* Kz = Kp + (long)z * Slen * 64;
  const half_t* Vz = Vp + (long)z * 64 * Slen;
  half_t* Kb0 = lds;
  half_t* Kb1 = lds + 4096;
  half_t* Vb  = lds + 8192;

  // prologue staging: K(0), V(0) (oldest 4 vmem ops, in this order)
  stageK64(Kz, sbeg, Kb0, tid);
  asm volatile("" ::: "memory");
  stageV64(Vz, sbeg, Slen, Vb, tid);
  asm volatile("" ::: "memory");

  half8 aQ[2][2];
#pragma unroll
  for (int mi = 0; mi < 2; ++mi)
#pragma unroll
    for (int k2 = 0; k2 < 2; ++k2)
      aQ[mi][k2] = *reinterpret_cast<const half8*>(
          Qz + (w * 32 + mi * 16 + r16) * 64 + k2 * 32 + g * 8);

  half8 vones;
#pragma unroll
  for (int j = 0; j < 8; ++j) vones[j] = (half_t)1.f;

  floatx4 oaccT[2][4];
  floatx4 lacc4[2];
#pragma unroll
  for (int mi = 0; mi < 2; ++mi) {
    lacc4[mi] = floatx4{0.f, 0.f, 0.f, 0.f};
#pragma unroll
    for (int no = 0; no < 4; ++no) oaccT[mi][no] = floatx4{0.f, 0.f, 0.f, 0.f};
  }

  const int send = sbeg + 512;
  int cur = 0;
  for (int s0 = sbeg; s0 < send; s0 += 64) {
    const bool hn = (s0 + 64 < send);
    // K(t) ready (V(t) = 2 newest still flying)
    asm volatile("s_waitcnt vmcnt(2)" ::: "memory");
    __builtin_amdgcn_s_barrier();
    asm volatile("" ::: "memory");

    unsigned int mb32[2];
    if constexpr (MASKED) {
      const int tile = s0 >> 7;
#pragma unroll
      for (int mi = 0; mi < 2; ++mi) {
        const int q = q0 + w * 32 + mi * 16 + r16;
        mb32[mi] = *reinterpret_cast<const unsigned int*>(
            mpk + ((long)q * NT + tile) * 16 + 4 * g);
      }
    }
    const int hf4 = ((s0 >> 6) & 1) ? 4 : 0;   // which 64-half of the 128-tile
    const unsigned int fullm = hf4 ? 0xf0f0f0f0u : 0x0f0f0f0fu;

    // S^T = K Q^T : 8 b128 reads feed 16 MFMAs
    floatx4 sacc[2][4];
#pragma unroll
    for (int mi = 0; mi < 2; ++mi)
#pragma unroll
      for (int ni = 0; ni < 4; ++ni) sacc[mi][ni] = floatx4{0.f, 0.f, 0.f, 0.f};
    const half_t* Kc = cur ? Kb1 : Kb0;
    __builtin_amdgcn_s_setprio(1);
#pragma unroll
    for (int ni = 0; ni < 4; ++ni) {
      const int rB = ni * 16 + r16;
      const half8 b0 = *reinterpret_cast<const half8*>(&Kc[rB * 64 + (g ^ (rB & 7)) * 8]);
      const half8 b1 = *reinterpret_cast<const half8*>(&Kc[rB * 64 + ((4 + g) ^ (rB & 7)) * 8]);
#pragma unroll
      for (int mi = 0; mi < 2; ++mi) {
        sacc[mi][ni] = __builtin_amdgcn_mfma_f32_16x16x32_f16(b0, aQ[mi][0], sacc[mi][ni], 0, 0, 0);
        sacc[mi][ni] = __builtin_amdgcn_mfma_f32_16x16x32_f16(b1, aQ[mi][1], sacc[mi][ni], 0, 0, 0);
      }
    }
    __builtin_amdgcn_s_setprio(0);
    // prefetch K(t+1) into the other buffer; lands under softmax+PV
    if (hn) stageK64(Kz, s0 + 64, cur ? Kb0 : Kb1, tid);
    asm volatile("" ::: "memory");

    // in-register softmax (separated phase): mask + exp2 only
#pragma unroll
    for (int mi = 0; mi < 2; ++mi) {
      if constexpr (MASKED) {
        if ((mb32[mi] & fullm) != fullm) {
#pragma unroll
          for (int reg = 0; reg < 4; ++reg)
#pragma unroll
            for (int ni = 0; ni < 4; ++ni)
              if (!((mb32[mi] >> (reg * 8 + ni + hf4)) & 1)) sacc[mi][ni][reg] = -__builtin_inff();
        }
      }
#pragma unroll
      for (int ni = 0; ni < 4; ++ni)
#pragma unroll
        for (int reg = 0; reg < 4; ++reg)
          sacc[mi][ni][reg] = __builtin_amdgcn_exp2f(sacc[mi][ni][reg]);
    }

    // V(t) ready (K(t+1) = newest 2 still in flight when hn)
    if (hn) { asm volatile("s_waitcnt vmcnt(2)" ::: "memory"); }
    else    { asm volatile("s_waitcnt vmcnt(0)" ::: "memory"); }
    __builtin_amdgcn_s_barrier();
    asm volatile("" ::: "memory");

    // O^T += V^T P^T ; l += ones·P^T (row-sum via matrix pipe)
#pragma unroll
    for (int c = 0; c < 2; ++c) {
      half8 bVv[4];
#pragma unroll
      for (int no = 0; no < 4; ++no) {
        const int rV = no * 16 + r16;
        bVv[no] = *reinterpret_cast<const half8*>(
            &Vb[rV * 64 + ((c * 4 + g) ^ (rV & 7)) * 8]);
      }
#pragma unroll
      for (int mi = 0; mi < 2; ++mi) {
        // butterfly P^T frag: target word p_t at lane g <-
        // pk[2c+(g>>1)][p_t&1] of lane 2(g&1)+(p_t>>1)
        int x0 = pkrtz(sacc[mi][2 * c][0],     sacc[mi][2 * c][1]);
        int x1 = pkrtz(sacc[mi][2 * c][2],     sacc[mi][2 * c][3]);
        int x2 = pkrtz(sacc[mi][2 * c + 1][0], sacc[mi][2 * c + 1][1]);
        int x3 = pkrtz(sacc[mi][2 * c + 1][2], sacc[mi][2 * c + 1][3]);
        pl32(x0, x2); pl32(x1, x3);   // resolve g1 <-> ni bit
        pl16(x0, x2); pl16(x1, x3);   // resolve g0 <-> word bit
        int4v wv; wv[0] = x0; wv[1] = x1; wv[2] = x2; wv[3] = x3;
        const half8 aP = __builtin_bit_cast(half8, wv);
        __builtin_amdgcn_s_setprio(1);
#pragma unroll
        for (int no = 0; no < 4; ++no)
          oaccT[mi][no] = __builtin_amdgcn_mfma_f32_16x16x32_f16(bVv[no], aP, oaccT[mi][no], 0, 0, 0);
        lacc4[mi] = __builtin_amdgcn_mfma_f32_16x16x32_f16(vones, aP, lacc4[mi], 0, 0, 0);
        __builtin_amdgcn_s_setprio(0);
      }
    }
    __builtin_amdgcn_s_barrier();
    asm volatile("" ::: "memory");
    // prefetch V(t+1); lands under next tile's QK^T + softmax
    if (hn) stageV64(Vz, s0 + 64, Slen, Vb, tid);
    asm volatile("" ::: "memory");
    cur ^= 1;
  }

  // epilogue: l_q sits in every lane's lacc4[mi][0] (col=lane&15=q).
  // per-wave f32 slab (4KB) lives in the Kb0/Kb1 region (16KB, reads done:
  // all waves passed the post-PV barrier after their last QK/PV reads).
  float ls2[2];
#pragma unroll
  for (int mi = 0; mi < 2; ++mi) ls2[mi] = lacc4[mi][0];

  float* slab = reinterpret_cast<float*>(lds) + w * 1024;
#pragma unroll
  for (int mi = 0; mi < 2; ++mi) {
    const int tq = q0 + w * 32 + mi * 16;
    if (lane < 16) Lp[(long)z * Tc + tq + r16] = ls2[mi];
#pragma unroll
    for (int no = 0; no < 4; ++no) {
      floatx4 v = oaccT[mi][no];
      *reinterpret_cast<floatx4*>(&slab[r16 * 64 + no * 16 + (g ^ (r16 & 3)) * 4]) = v;
    }
#pragma unroll
    for (int it = 0; it < 4; ++it) {
      const int q2 = it * 4 + g;
      const int d4 = r16;
      const floatx4 v = *reinterpret_cast<const floatx4*>(
          &slab[q2 * 64 + (d4 >> 2) * 16 + ((d4 & 3) ^ (q2 & 3)) * 4]);
      const long off = ((long)(b * Tc + tq + q2)) * Cc + h * 64 + d4 * 4;
      half4v hh; hh[0] = (half_t)v[0]; hh[1] = (half_t)v[1];
      hh[2] = (half_t)v[2]; hh[3] = (half_t)v[3];
      *reinterpret_cast<half4v*>(&POh[off]) = hh;   // unnormalized f16
    }
  }
}

// 1536 blocks, each exactly 8 s-tiles of 64 (24KB LDS; launch_bounds(256,4)
// keeps natural regalloc — no spills):
//  bx < 1024: att0 (chained, masked), s-quarter qt -> slabs 0-3
//  bx >= 1024: att1 (first), s-half sh -> slabs 4-5
__global__ __launch_bounds__(256, 4) void flash_both(
    const half_t* __restrict__ Q2, const half_t* __restrict__ KX,
    const half_t* __restrict__ VXT, const unsigned char* __restrict__ mpk,
    const half_t* __restrict__ QX, const half_t* __restrict__ KY,
    const half_t* __restrict__ VYT,
    half_t* __restrict__ POh, float* __restrict__ Lp)
{
  __shared__ __align__(16) half_t lds[12288];   // 24 KB
  const int bx = blockIdx.x;
  if (bx < 1024) {
    const int z  = ((bx & 7) << 1) | ((bx >> 3) & 1);   // z-local per XCD
    const int qt = (bx >> 4) & 3;
    const int q0 = (bx >> 6) * 128;
    flash_body<true>(Q2, KX, VXT, mpk,
                     POh + (long)qt * BTC, Lp + (long)qt * ZT,
                     Tc, qt * 512, z, q0, lds);
  } else {
    const int b2 = bx - 1024;
    const int z  = ((b2 & 7) << 1) | ((b2 >> 3) & 1);
    const int sh = (b2 >> 4) & 1;
    const int q0 = (b2 >> 5) * 128;
    flash_body<false>(QX, KY, VYT, nullptr,
                      POh + (long)(4 + sh) * BTC, Lp + (long)(4 + sh) * ZT,
                      Mc, sh * 512, z, q0, lds);
  }
}

// --------------------------- combine 6 slabs -> DH
// DH = (O4+O5)/(l4+l5) - (O0+O1+O2+O3)/(l0+l1+l2+l3)
__global__ __launch_bounds__(256) void combine_k(
    const half_t* __restrict__ POh, const float* __restrict__ Lp,
    half_t* __restrict__ DH)
{
  const long idx = (long)blockIdx.x * 256 + threadIdx.x;   // over BTC/4
  const long c4 = idx * 4;
  const int c = (int)(c4 & (Cc - 1));
  const long bt = c4 >> 9;
  const int h = c >> 6;
  const int b = (int)(bt >> 11), t = (int)(bt & (Tc - 1));
  const long zt = (long)(b * Hc + h) * Tc + t;
  const float i0 = 1.f / (Lp[zt] + Lp[ZT + zt] + Lp[2 * ZT + zt] + Lp[3 * ZT + zt]);
  const float i1 = 1.f / (Lp[4 * ZT + zt] + Lp[5 * ZT + zt]);
  float a0[4] = {0.f, 0.f, 0.f, 0.f}, a1[4] = {0.f, 0.f, 0.f, 0.f};
#pragma unroll
  for (int s = 0; s < 4; ++s) {
    const half4v o = reinterpret_cast<const half4v*>(POh)[s * (BTC / 4) + idx];
#pragma unroll
    for (int j = 0; j < 4; ++j) a0[j] += (float)o[j];
  }
#pragma unroll
  for (int s = 4; s < 6; ++s) {
    const half4v o = reinterpret_cast<const half4v*>(POh)[s * (BTC / 4) + idx];
#pragma unroll
    for (int j = 0; j < 4; ++j) a1[j] += (float)o[j];
  }
  half4v r;
#pragma unroll
  for (int j = 0; j < 4; ++j) r[j] = (half_t)(a1[j] * i1 - a0[j] * i0);
  reinterpret_cast<half4v*>(DH)[idx] = r;
}

// ----------------------------------------------- prep: converts + mask pack
__device__ __forceinline__ void cvt4(const float* in, half_t* out, long i) {
  const float4 f = reinterpret_cast<const float4*>(in)[i];
  half4v h; h[0] = (half_t)f.x; h[1] = (half_t)f.y; h[2] = (half_t)f.z; h[3] = (half_t)f.w;
  reinterpret_cast<half4v*>(out)[i] = h;
}

__global__ __launch_bounds__(256) void prep(
    const float* __restrict__ x, const float* __restrict__ y,
    const float* __restrict__ qw, const float* __restrict__ pw,
    const int* __restrict__ mask,
    half_t* __restrict__ XH, half_t* __restrict__ YH,
    half_t* __restrict__ WQ, half_t* __restrict__ WP,
    unsigned char* __restrict__ mpk)
{
  const long i = (long)blockIdx.x * 256 + threadIdx.x;
  constexpr long n0 = 524288;            // x/4
  constexpr long n1 = n0 + 262144;       // y/4
  constexpr long n2 = n1 + 196608;       // qkv_w/4
  constexpr long n3 = n2 + 65536;        // proj_w/4
  if (i < n0) cvt4(x, XH, i);
  else if (i < n1) cvt4(y, YH, i - n0);
  else if (i < n2) cvt4(qw, WQ, i - n1);
  else if (i < n3) cvt4(pw, WP, i - n2);
  else {
    const long idx = i - n3;             // [0, Tc*256)
    const int t = (int)(idx >> 8), tile = (int)((idx >> 4) & 15), r16 = (int)(idx & 15);
    const int* row = mask + (long)t * Tc + tile * 128 + r16;
    unsigned int bbits = 0;
#pragma unroll
    for (int ni = 0; ni < 8; ++ni)
      bbits |= (row[ni * 16] != 0 ? 1u : 0u) << ni;
    mpk[idx] = (unsigned char)bbits;
  }
}

// ------------------------------------------------------------- workspace map
constexpr size_t OFF_XH   = 0;                                   // [B*T,C] f16 (YH must follow!)
constexpr size_t OFF_YH   = OFF_XH   + (size_t)Bc*Tc*Cc*2;       // contiguous rows after XH
constexpr size_t OFF_WQ   = OFF_YH   + (size_t)Bc*Mc*Cc*2;
constexpr size_t OFF_WP   = OFF_WQ   + (size_t)3*Cc*Cc*2;
constexpr size_t OFF_QX   = OFF_WP   + (size_t)Cc*Cc*2;          // [z,T,D] *0.125*log2e
constexpr size_t OFF_KX   = OFF_QX   + (size_t)Bc*Hc*Tc*Dc*2;    // [z,T,D]
constexpr size_t OFF_VXT  = OFF_KX   + (size_t)Bc*Hc*Tc*Dc*2;    // [z,D,T]
constexpr size_t OFF_QYT  = OFF_VXT  + (size_t)Bc*Hc*Tc*Dc*2;    // [z,D,M] *0.125
constexpr size_t OFF_KY   = OFF_QYT  + (size_t)Bc*Hc*Mc*Dc*2;    // [z,M,D]
constexpr size_t OFF_KYT  = OFF_KY   + (size_t)Bc*Hc*Mc*Dc*2;    // [z,D,M]
constexpr size_t OFF_VYT  = OFF_KYT  + (size_t)Bc*Hc*Mc*Dc*2;    // [z,D,M]
constexpr size_t OFF_Q2   = OFF_VYT  + (size_t)Bc*Hc*Mc*Dc*2;    // [z,T,D]
constexpr size_t OFF_DH   = OFF_Q2   + (size_t)Bc*Hc*Tc*Dc*2;    // [B,T,C] diff f16
constexpr size_t OFF_MPK  = OFF_DH   + (size_t)Bc*Tc*Cc*2;       // [T,16,16] u8
constexpr size_t OFF_PO   = OFF_MPK  + (size_t)Tc*256;           // [6][B,T,C] f16 unnormalized
constexpr size_t OFF_L    = OFF_PO   + (size_t)6*BTC*2;          // [6][ZT] f32 row sums
// total ~65 MB

extern "C" void kernel_launch(void* const* d_in, const int* in_sizes, int n_in,
                              void* d_out, int out_size, void* d_ws, size_t ws_size,
                              hipStream_t stream) {
  const float* x      = (const float*)d_in[0];
  const float* y      = (const float*)d_in[1];
  const int*   mask   = (const int*)  d_in[2];
  const float* qkv_b  = (const float*)d_in[4];
  const float* proj_b = (const float*)d_in[6];
  float* out = (float*)d_out;
  char* ws = (char*)d_ws;

  half_t* XH   = (half_t*)(ws + OFF_XH);
  half_t* YH   = (half_t*)(ws + OFF_YH);
  half_t* WQ   = (half_t*)(ws + OFF_WQ);
  half_t* WP   = (half_t*)(ws + OFF_WP);
  half_t* QX   = (half_t*)(ws + OFF_QX);
  half_t* KX   = (half_t*)(ws + OFF_KX);
  half_t* VXT  = (half_t*)(ws + OFF_VXT);
  half_t* QYT  = (half_t*)(ws + OFF_QYT);
  half_t* KY   = (half_t*)(ws + OFF_KY);
  half_t* KYT  = (half_t*)(ws + OFF_KYT);
  half_t* VYT  = (half_t*)(ws + OFF_VYT);
  half_t* Q2   = (half_t*)(ws + OFF_Q2);
  half_t* DH   = (half_t*)(ws + OFF_DH);
  unsigned char* MPK = (unsigned char*)(ws + OFF_MPK);
  half_t* POh  = (half_t*)(ws + OFF_PO);
  float*  Lp   = (float*) (ws + OFF_L);

  // converts + mask packing (one launch)
  prep<<<6144, 256, 0, stream>>>(x, y, (const float*)d_in[3], (const float*)d_in[5],
                                 mask, XH, YH, WQ, WP, MPK);

  // fused qkv projection for x and y (XH||YH contiguous: 6144 rows)
  {
    EpiParams ep{};
    ep.h0 = QX; ep.h1 = KX; ep.h2 = VXT; ep.h3 = QYT;
    ep.h4 = KY; ep.h5 = KYT; ep.h6 = VYT; ep.bias = qkv_b;
    gemm_nt<128,64,2,2,EPI_QKV_XY,24,48><<<dim3(24, 48, 1), 256, 0, stream>>>(
        XH, WQ, Cc, Cc, Cc, 0, 0, ep);
  }

  // fused WT+Q2: 512 flat blocks (2/CU), XCD remap
  wtq2<<<dim3(512), 256, 0, stream>>>(QYT, KYT, QX, Q2);

  // occupancy-unlocked flash: 1024 att0-quarter + 512 att1-half = 1536
  flash_both<<<dim3(1536), 256, 0, stream>>>(
      Q2, KX, VXT, MPK, QX, KY, VYT, POh, Lp);

  // combine 6 slabs -> DH
  combine_k<<<(int)(BTC/4/256), 256, 0, stream>>>(POh, Lp, DH);

  // out = DH @ proj_w^T + proj_b  (BN=32: 1024 blocks = 4/CU, XCD remap)
  {
    EpiParams ep{}; ep.f0 = out; ep.bias = proj_b;
    gemm_nt<64,32,2,2,EPI_PROJ,16,64><<<dim3(16, 64, 1), 256, 0, stream>>>(
        DH, WP, Cc, Cc, Cc, 0, 0, ep);
  }
}

// Round 14
// 168.844 us; speedup vs baseline: 1.0166x; 1.0166x over previous
//
#include <hip/hip_runtime.h>

// CrossAttentionPro on MI355X — Round 26:
//  Cache-hint polish (all math bit-identical to R25):
//   - flash PO stores nontemporal: 48MB of once-written/once-read stream
//     no longer evicts K/V panels from each XCD's 4MB L2 (they're re-read
//     by 16 q-blocks per z).
//   - combine: half8 (16B) slab loads, nontemporal (never re-read);
//     1024 blocks; same per-element accumulation order.
//  Kept: R23 flash (64-s tiles, 1536 blocks = 6/CU by LDS at VGPR 64,
//  R19 rhythm: 3 barriers/tile, K dbuf, counted vmcnt(2), separated
//  no-max exp2 softmax, ones-MFMA row-sum, pkrtz+permlane P-frag
//  butterfly, setprio), swapped-operand S^T=mfma(K,Q), coalesced qkv
//  epilogue via LDS slab, f16 PO slabs + 6-slab combine, bit-packed mask,
//  XCD z-locality, XCD-chunked GEMM remaps, wtq2@512, proj BN=32@1024.

typedef _Float16 half_t;
typedef _Float16 half8 __attribute__((ext_vector_type(8)));
typedef _Float16 half4v __attribute__((ext_vector_type(4)));
typedef float floatx4 __attribute__((ext_vector_type(4)));
typedef int int4v __attribute__((ext_vector_type(4)));
typedef int int2v __attribute__((ext_vector_type(2)));

constexpr int Bc = 2, Tc = 2048, Mc = 1024, Cc = 512, Hc = 8, Dc = 64;
constexpr long BTC = (long)Bc * Tc * Cc;
constexpr long ZT  = (long)Bc * Hc * Tc;
constexpr float S1 = 0.18033688f;                 // 0.125 * log2(e)

enum { EPI_F16STORE = 0, EPI_QKV_XY = 1, EPI_PROJ = 2 };

struct EpiParams {
  half_t* h0;        // QXs  / f16 dest
  half_t* h1;        // KX
  half_t* h2;        // VXT
  half_t* h3;        // QYT
  half_t* h4;        // KY
  half_t* h5;        // KYT
  half_t* h6;        // VYT
  float* f0;
  const float* bias;
  float scale;
  int ldc;
  long bstride;
};

// async global->LDS, 16B per lane; dst must be wave-uniform base + lane*16.
__device__ __forceinline__ void gld_lds16(const half_t* g, half_t* l) {
  __builtin_amdgcn_global_load_lds(
      (const __attribute__((address_space(1))) void*)g,
      (__attribute__((address_space(3))) void*)l, 16, 0, 0);
}

// pack 2 f32 -> 2 f16 (RTZ) as one u32
__device__ __forceinline__ int pkrtz(float a, float b) {
  return __builtin_bit_cast(int, __builtin_amdgcn_cvt_pkrtz(a, b));
}
// v_permlane16_swap: a.row1<->b.row0, a.row3<->b.row2 (rows = 16-lane groups)
__device__ __forceinline__ void pl16(int& a, int& b) {
  asm volatile("v_permlane16_swap_b32 %0, %1" : "+v"(a), "+v"(b));
}
// v_permlane32_swap: a.rows{2,3} <-> b.rows{0,1}
__device__ __forceinline__ void pl32(int& a, int& b) {
  asm volatile("v_permlane32_swap_b32 %0, %1" : "+v"(a), "+v"(b));
}

// ---------------------------------------------------------------- GEMM (NT)
// C[r,c] = sum_k A[r,k]*Bt[c,k]. BK=64 double-buffered async staging with
// counted vmcnt, swizzled chunks (conflict-free ds_read_b128).
// GX/GY: logical grid dims for XCD-chunked remap (0 = no remap).
template <int BM, int BN, int WMG, int WNG, int EPI, int GX = 0, int GY = 0>
__global__ __launch_bounds__(256) void gemm_nt(
    const half_t* __restrict__ A, const half_t* __restrict__ Bt,
    int K, int lda, int ldb, long bsA, long bsB, EpiParams ep)
{
  constexpr int BK = 64;
  constexpr int WTM = BM / WMG, WTN = BN / WNG;
  constexpr int MI = WTM / 16, NI = WTN / 16;
  constexpr int AIT = BM * BK / 8 / 256;
  constexpr int BIT = BN * BK / 8 / 256;
  constexpr int NLD = AIT + BIT;
  __shared__ __align__(16) half_t As[2][BM * BK];
  __shared__ __align__(16) half_t Bs[2][BN * BK];

  const int tid = threadIdx.x;
  const int lane = tid & 63;
  const int wave = tid >> 6;
  const int wm = wave / WNG, wn = wave % WNG;
  const int r16 = lane & 15, g = lane >> 4;
  const int z = blockIdx.z;

  int bxl = blockIdx.x, byl = blockIdx.y;
  if constexpr (GX > 0) {
    constexpr int CHUNK = GX * GY / 8;   // GX*GY % 8 == 0 required
    const int f = byl * GX + bxl;
    const int L = (f & 7) * CHUNK + (f >> 3);
    bxl = L % GX; byl = L / GX;
  }
  const long m0 = (long)byl * BM;
  const long n0 = (long)bxl * BN;
  const half_t* Abase = A + (long)z * bsA + m0 * (long)lda;
  const half_t* Bbase = Bt + (long)z * bsB + n0 * (long)ldb;

  const int rA = wm * WTM + r16;
  const int rB = wn * WTN + r16;

  floatx4 acc[MI][NI];
#pragma unroll
  for (int mi = 0; mi < MI; ++mi)
#pragma unroll
    for (int ni = 0; ni < NI; ++ni)
      acc[mi][ni] = floatx4{0.f, 0.f, 0.f, 0.f};

  auto stage = [&](int kt, int buf) {
#pragma unroll
    for (int i = 0; i < AIT; ++i) {
      const int c = tid + i * 256;
      const int row = c >> 3, js = c & 7;
      const int jg = js ^ (row & 7);
      gld_lds16(Abase + (long)row * lda + kt + jg * 8, &As[buf][c * 8]);
    }
#pragma unroll
    for (int i = 0; i < BIT; ++i) {
      const int c = tid + i * 256;
      const int row = c >> 3, js = c & 7;
      const int jg = js ^ (row & 7);
      gld_lds16(Bbase + (long)row * ldb + kt + jg * 8, &Bs[buf][c * 8]);
    }
  };

  const int NIT = K / BK;
  stage(0, 0);
  asm volatile("" ::: "memory");

  for (int it = 0; it < NIT; ++it) {
    const bool hn = (it + 1 < NIT);
    if (hn) stage((it + 1) * BK, (it + 1) & 1);
    asm volatile("" ::: "memory");
    if (hn) {
      if constexpr (NLD == 6) asm volatile("s_waitcnt vmcnt(6)" ::: "memory");
      else if constexpr (NLD == 4) asm volatile("s_waitcnt vmcnt(4)" ::: "memory");
      else if constexpr (NLD == 3) asm volatile("s_waitcnt vmcnt(3)" ::: "memory");
      else if constexpr (NLD == 8) asm volatile("s_waitcnt vmcnt(8)" ::: "memory");
      else asm volatile("s_waitcnt vmcnt(0)" ::: "memory");
    } else {
      asm volatile("s_waitcnt vmcnt(0)" ::: "memory");
    }
    __builtin_amdgcn_s_barrier();
    asm volatile("" ::: "memory");

    const half_t* Ab = As[it & 1];
    const half_t* Bb = Bs[it & 1];
    half8 aF[MI][2], bF[NI][2];
#pragma unroll
    for (int mi = 0; mi < MI; ++mi)
#pragma unroll
      for (int k2 = 0; k2 < 2; ++k2)
        aF[mi][k2] = *reinterpret_cast<const half8*>(
            &Ab[(rA + mi * 16) * BK + ((k2 * 4 + g) ^ (r16 & 7)) * 8]);
#pragma unroll
    for (int ni = 0; ni < NI; ++ni)
#pragma unroll
      for (int k2 = 0; k2 < 2; ++k2)
        bF[ni][k2] = *reinterpret_cast<const half8*>(
            &Bb[(rB + ni * 16) * BK + ((k2 * 4 + g) ^ (r16 & 7)) * 8]);
    __builtin_amdgcn_s_setprio(1);
#pragma unroll
    for (int k2 = 0; k2 < 2; ++k2)
#pragma unroll
      for (int mi = 0; mi < MI; ++mi)
#pragma unroll
        for (int ni = 0; ni < NI; ++ni)
          acc[mi][ni] = __builtin_amdgcn_mfma_f32_16x16x32_f16(
              aF[mi][k2], bF[ni][k2], acc[mi][ni], 0, 0, 0);
    __builtin_amdgcn_s_setprio(0);
    asm volatile("s_waitcnt lgkmcnt(0)" ::: "memory");
    __builtin_amdgcn_s_barrier();
    asm volatile("" ::: "memory");
  }

  // epilogue: C/D layout col=lane&15, row=(lane>>4)*4+reg  [m89-verified]
  // transposed-output slab (reuses As, free after last barrier): [64][136]
  half_t* Txp = &As[0][0];
  const bool isx  = (m0 < (long)Bc * Tc);
  const int which = (int)(n0 >> 9);
  const int hh    = ((int)n0 & 511) >> 6;

#pragma unroll
  for (int mi = 0; mi < MI; ++mi) {
#pragma unroll
    for (int ni = 0; ni < NI; ++ni) {
#pragma unroll
      for (int reg = 0; reg < 4; ++reg) {
        const int r = (int)m0 + wm * WTM + mi * 16 + g * 4 + reg;
        const int c = (int)n0 + wn * WTN + ni * 16 + r16;
        const float v = acc[mi][ni][reg];
        if constexpr (EPI == EPI_F16STORE) {
          ep.h0[(long)z * ep.bstride + (long)r * ep.ldc + c] = (half_t)(v * ep.scale);
        } else if constexpr (EPI == EPI_QKV_XY) {
          const float val = v + ep.bias[c];
          const int d = c & 63;
          const int rloc = r - (int)m0;
          if (isx) {                    // x rows
            const int b = (int)(m0 >> 11);
            const int t = r & (Tc - 1);
            const long bh = (long)(b * Hc + hh);
            if (which == 0)      ep.h0[(bh * Tc + t) * Dc + d] = (half_t)(val * S1);  // QXs
            else if (which == 1) ep.h1[(bh * Tc + t) * Dc + d] = (half_t)val;         // KX
            else                 Txp[d * 136 + rloc] = (half_t)val;                   // VXT (LDS)
          } else {                      // y rows
            const long m2 = m0 - (long)Bc * Tc;
            const int b = (int)(m2 >> 10);
            const int t = (r - Bc * Tc) & (Mc - 1);
            const long bh = (long)(b * Hc + hh);
            if (which == 0)      Txp[d * 136 + rloc] = (half_t)(val * 0.125f);        // QYT (LDS)
            else if (which == 1) { ep.h4[(bh * Mc + t) * Dc + d] = (half_t)val;       // KY
                                   Txp[d * 136 + rloc] = (half_t)val; }               // KYT (LDS)
            else                 Txp[d * 136 + rloc] = (half_t)val;                   // VYT (LDS)
          }
        } else {  // EPI_PROJ
          ep.f0[(long)r * Cc + c] = v + ep.bias[c];
        }
      }
    }
  }

  if constexpr (EPI == EPI_QKV_XY && BM == 128) {
    const bool hasT = isx ? (which == 2) : true;
    if (hasT) {                     // block-uniform -> barrier is safe
      __syncthreads();
      half_t* dstT; int L; long tb; int b;
      if (isx) { dstT = ep.h2; L = Tc; tb = m0 & (Tc - 1); b = (int)(m0 >> 11); }
      else {
        const long m2 = m0 - (long)Bc * Tc;
        b = (int)(m2 >> 10); tb = m2 & (Mc - 1); L = Mc;
        dstT = (which == 0) ? ep.h3 : (which == 1) ? ep.h5 : ep.h6;
      }
      const long bh = (long)(b * Hc + hh);
      const int dr = tid >> 2, qd = tid & 3;       // 64 rows x 4 quarters
      half_t* gbase = dstT + (bh * 64 + dr) * L + tb + qd * 32;
#pragma unroll
      for (int j = 0; j < 4; ++j) {
        const half8 v8 = *reinterpret_cast<const half8*>(&Txp[dr * 136 + qd * 32 + j * 8]);
        *reinterpret_cast<half8*>(&gbase[j * 8]) = v8;
      }
    }
  }
}

// --------------------------------------------- fused WT+Q2 kernel
// grid 512 flat (2 blocks/CU); logical (t-chunk of 64, z) via XCD-chunked
// remap (same-z blocks co-locate -> QYT/KYT panel reads L2-hot).
// Phase 1: WT[64][64] = 0.125 * QYTs[z] KYT[z]^T (K=1024, pipelined dbuf)
// -> LDS in phase-2 fragment layout (computed redundantly per t-chunk).
// Phase 2: Q2[z, t0..t0+63, :] = QXs * WT^T (K=64, MI=1: 16 rows/wave).
__global__ __launch_bounds__(256) void wtq2(
    const half_t* __restrict__ QYT, const half_t* __restrict__ KYT,
    const half_t* __restrict__ QX, half_t* __restrict__ Q2)
{
  __shared__ __align__(16) half_t As[2][4096];
  __shared__ __align__(16) half_t Bs[2][4096];
  __shared__ __align__(16) half_t WTs[4096];
  const int tid = threadIdx.x, lane = tid & 63, wave = tid >> 6;
  const int wm = wave >> 1, wn = wave & 1;
  const int r16 = lane & 15, g = lane >> 4;
  const int f = blockIdx.x;
  const int L = (f & 7) * 64 + (f >> 3);   // 512 blocks, chunk=64
  const int z = L >> 5;                    // 32 t-chunks per z
  const int t0 = (L & 31) * 64;
  const half_t* Aq = QYT + (long)z * Dc * Mc;
  const half_t* Bk = KYT + (long)z * Dc * Mc;

  auto stage1 = [&](int kt, int buf) {
#pragma unroll
    for (int i = 0; i < 2; ++i) {
      const int c = tid + i * 256;
      const int row = c >> 3, js = c & 7, jg = js ^ (row & 7);
      gld_lds16(Aq + (long)row * Mc + kt + jg * 8, &As[buf][c * 8]);
    }
#pragma unroll
    for (int i = 0; i < 2; ++i) {
      const int c = tid + i * 256;
      const int row = c >> 3, js = c & 7, jg = js ^ (row & 7);
      gld_lds16(Bk + (long)row * Mc + kt + jg * 8, &Bs[buf][c * 8]);
    }
  };

  floatx4 acc[2][2];
#pragma unroll
  for (int mi = 0; mi < 2; ++mi)
#pragma unroll
    for (int ni = 0; ni < 2; ++ni) acc[mi][ni] = floatx4{0.f, 0.f, 0.f, 0.f};

  const int rA = wm * 32 + r16, rB = wn * 32 + r16;
  stage1(0, 0);
  asm volatile("" ::: "memory");
  for (int it = 0; it < 16; ++it) {
    const bool hn = (it < 15);
    if (hn) stage1((it + 1) * 64, (it + 1) & 1);
    asm volatile("" ::: "memory");
    if (hn) asm volatile("s_waitcnt vmcnt(4)" ::: "memory");
    else    asm volatile("s_waitcnt vmcnt(0)" ::: "memory");
    __builtin_amdgcn_s_barrier();
    asm volatile("" ::: "memory");
    const half_t* Ab = As[it & 1];
    const half_t* Bb = Bs[it & 1];
    half8 aF[2][2], bF[2][2];
#pragma unroll
    for (int mi = 0; mi < 2; ++mi)
#pragma unroll
      for (int k2 = 0; k2 < 2; ++k2)
        aF[mi][k2] = *reinterpret_cast<const half8*>(
            &Ab[(rA + mi * 16) * 64 + ((k2 * 4 + g) ^ (r16 & 7)) * 8]);
#pragma unroll
    for (int ni = 0; ni < 2; ++ni)
#pragma unroll
      for (int k2 = 0; k2 < 2; ++k2)
        bF[ni][k2] = *reinterpret_cast<const half8*>(
            &Bb[(rB + ni * 16) * 64 + ((k2 * 4 + g) ^ (r16 & 7)) * 8]);
    __builtin_amdgcn_s_setprio(1);
#pragma unroll
    for (int k2 = 0; k2 < 2; ++k2)
#pragma unroll
      for (int mi = 0; mi < 2; ++mi)
#pragma unroll
        for (int ni = 0; ni < 2; ++ni)
          acc[mi][ni] = __builtin_amdgcn_mfma_f32_16x16x32_f16(
              aF[mi][k2], bF[ni][k2], acc[mi][ni], 0, 0, 0);
    __builtin_amdgcn_s_setprio(0);
    asm volatile("s_waitcnt lgkmcnt(0)" ::: "memory");
    __builtin_amdgcn_s_barrier();
    asm volatile("" ::: "memory");
  }

  // phase-2 A stage (As fully free after final barrier): QX rows t0..t0+63
  half_t* P2 = &As[0][0];
#pragma unroll
  for (int i = 0; i < 2; ++i) {
    const int c = tid + i * 256;
    const int row = c >> 3, js = c & 7, jg = js ^ (row & 7);
    gld_lds16(QX + ((long)z * Tc + t0 + row) * 64 + jg * 8, P2 + c * 8);
  }
  // WT -> LDS f16 in phase-2 fragment layout (chunk swizzle js^(row&7))
#pragma unroll
  for (int mi = 0; mi < 2; ++mi)
#pragma unroll
    for (int ni = 0; ni < 2; ++ni)
#pragma unroll
      for (int reg = 0; reg < 4; ++reg) {
        const int r = wm * 32 + mi * 16 + g * 4 + reg;   // d2
        const int c = wn * 32 + ni * 16 + r16;           // d1
        WTs[r * 64 + (((c >> 3) ^ (r & 7)) << 3) + (c & 7)] =
            (half_t)(acc[mi][ni][reg] * 0.125f);
      }
  __syncthreads();   // drains vmcnt (QX stage) + lgkm (WTs writes)

  // phase 2: per wave 16 t-rows (MI=1), full 64 d2 cols, K=64
  floatx4 a2[4];
#pragma unroll
  for (int ni = 0; ni < 4; ++ni) a2[ni] = floatx4{0.f, 0.f, 0.f, 0.f};
  const int rA2 = wave * 16 + r16;
  half8 aF2[2], bF2[4][2];
#pragma unroll
  for (int k2 = 0; k2 < 2; ++k2)
    aF2[k2] = *reinterpret_cast<const half8*>(
        &P2[rA2 * 64 + ((k2 * 4 + g) ^ (r16 & 7)) * 8]);
#pragma unroll
  for (int ni = 0; ni < 4; ++ni)
#pragma unroll
    for (int k2 = 0; k2 < 2; ++k2)
      bF2[ni][k2] = *reinterpret_cast<const half8*>(
          &WTs[(ni * 16 + r16) * 64 + ((k2 * 4 + g) ^ (r16 & 7)) * 8]);
#pragma unroll
  for (int k2 = 0; k2 < 2; ++k2)
#pragma unroll
    for (int ni = 0; ni < 4; ++ni)
      a2[ni] = __builtin_amdgcn_mfma_f32_16x16x32_f16(
          aF2[k2], bF2[ni][k2], a2[ni], 0, 0, 0);
#pragma unroll
  for (int ni = 0; ni < 4; ++ni)
#pragma unroll
    for (int reg = 0; reg < 4; ++reg) {
      const int t = t0 + wave * 16 + g * 4 + reg;
      const int c = ni * 16 + r16;
      Q2[((long)z * Tc + t) * 64 + c] = (half_t)a2[ni][reg];
    }
}

// ------------------------------------------------------------ flash staging
// s-tile 64: K tile [64 s][64 d] = 8KB, V^T tile [64 d][64 s] = 8KB.
// 2 gld_lds16 per thread each (counted vmcnt relies on this).
__device__ __forceinline__ void stageK64(const half_t* Kz, int s0, half_t* dst, int tid) {
#pragma unroll
  for (int i = 0; i < 2; ++i) {
    const int c = tid + i * 256;
    const int row = c >> 3, js = c & 7;
    const int jg = js ^ (row & 7);
    gld_lds16(Kz + (long)(s0 + row) * 64 + jg * 8, dst + c * 8);
  }
}
__device__ __forceinline__ void stageV64(const half_t* Vz, int s0, int Slen, half_t* dst, int tid) {
#pragma unroll
  for (int i = 0; i < 2; ++i) {
    const int c = tid + i * 256;
    const int row = c >> 3, js = c & 7;
    const int jg = js ^ (row & 7);
    gld_lds16(Vz + (long)row * Slen + s0 + jg * 8, dst + c * 8);
  }
}

// --------------------------------------------------------- flash body (MI=2)
// 128 q-rows/block, 8 s-tiles of 64 over [sbeg, sbeg+512). R19 rhythm:
//  vmcnt(2)+barrier [K(t) ready] ; QK MFMA cluster ; issue K(t+1) ; softmax
//  (mask+exp2) ; vmcnt(2)+barrier [V(t) ready] ; PV (+ones-MFMA row-sum) ;
//  barrier ; issue V(t+1). Always partial: unnormalized O f16 + row-sum L.
// lds layout (24KB): Kb0 = lds[0..4096), Kb1 = [4096..8192), Vb = [8192..12288)
template <bool MASKED>
__device__ __forceinline__ void flash_body(
    const half_t* __restrict__ Qp, const half_t* __restrict__ Kp,
    const half_t* __restrict__ Vp, const unsigned char* __restrict__ mpk,
    half_t* __restrict__ POh, float* __restrict__ Lp,
    int Slen, int sbeg, int z, int q0, half_t* lds)
{
  const int tid = threadIdx.x, lane = tid & 63, w = tid >> 6;
  const int r16 = lane & 15, g = lane >> 4;
  const int b = z >> 3, h = z & 7;
  const int NT = Slen >> 7;                 // 128-tile count (mask indexing)
  const half_t* Qz = Qp + ((long)z * Tc + q0) * 64;
  const half_t* Kz = Kp + (long)z * Slen * 64;
  const half_t* Vz = Vp + (long)z * 64 * Slen;
  half_t* Kb0 = lds;
  half_t* Kb1 = lds + 4096;
  half_t* Vb  = lds + 8192;

  // prologue staging: K(0), V(0) (oldest 4 vmem ops, in this order)
  stageK64(Kz, sbeg, Kb0, tid);
  asm volatile("" ::: "memory");
  stageV64(Vz, sbeg, Slen, Vb, tid);
  asm volatile("" ::: "memory");

  half8 aQ[2][2];
#pragma unroll
  for (int mi = 0; mi < 2; ++mi)
#pragma unroll
    for (int k2 = 0; k2 < 2; ++k2)
      aQ[mi][k2] = *reinterpret_cast<const half8*>(
          Qz + (w * 32 + mi * 16 + r16) * 64 + k2 * 32 + g * 8);

  half8 vones;
#pragma unroll
  for (int j = 0; j < 8; ++j) vones[j] = (half_t)1.f;

  floatx4 oaccT[2][4];
  floatx4 lacc4[2];
#pragma unroll
  for (int mi = 0; mi < 2; ++mi) {
    lacc4[mi] = floatx4{0.f, 0.f, 0.f, 0.f};
#pragma unroll
    for (int no = 0; no < 4; ++no) oaccT[mi][no] = floatx4{0.f, 0.f, 0.f, 0.f};
  }

  const int send = sbeg + 512;
  int cur = 0;
  for (int s0 = sbeg; s0 < send; s0 += 64) {
    const bool hn = (s0 + 64 < send);
    // K(t) ready (V(t) = 2 newest still flying)
    asm volatile("s_waitcnt vmcnt(2)" ::: "memory");
    __builtin_amdgcn_s_barrier();
    asm volatile("" ::: "memory");

    unsigned int mb32[2];
    if constexpr (MASKED) {
      const int tile = s0 >> 7;
#pragma unroll
      for (int mi = 0; mi < 2; ++mi) {
        const int q = q0 + w * 32 + mi * 16 + r16;
        mb32[mi] = *reinterpret_cast<const unsigned int*>(
            mpk + ((long)q * NT + tile) * 16 + 4 * g);
      }
    }
    const int hf4 = ((s0 >> 6) & 1) ? 4 : 0;   // which 64-half of the 128-tile
    const unsigned int fullm = hf4 ? 0xf0f0f0f0u : 0x0f0f0f0fu;

    // S^T = K Q^T : 8 b128 reads feed 16 MFMAs
    floatx4 sacc[2][4];
#pragma unroll
    for (int mi = 0; mi < 2; ++mi)
#pragma unroll
      for (int ni = 0; ni < 4; ++ni) sacc[mi][ni] = floatx4{0.f, 0.f, 0.f, 0.f};
    const half_t* Kc = cur ? Kb1 : Kb0;
    __builtin_amdgcn_s_setprio(1);
#pragma unroll
    for (int ni = 0; ni < 4; ++ni) {
      const int rB = ni * 16 + r16;
      const half8 b0 = *reinterpret_cast<const half8*>(&Kc[rB * 64 + (g ^ (rB & 7)) * 8]);
      const half8 b1 = *reinterpret_cast<const half8*>(&Kc[rB * 64 + ((4 + g) ^ (rB & 7)) * 8]);
#pragma unroll
      for (int mi = 0; mi < 2; ++mi) {
        sacc[mi][ni] = __builtin_amdgcn_mfma_f32_16x16x32_f16(b0, aQ[mi][0], sacc[mi][ni], 0, 0, 0);
        sacc[mi][ni] = __builtin_amdgcn_mfma_f32_16x16x32_f16(b1, aQ[mi][1], sacc[mi][ni], 0, 0, 0);
      }
    }
    __builtin_amdgcn_s_setprio(0);
    // prefetch K(t+1) into the other buffer; lands under softmax+PV
    if (hn) stageK64(Kz, s0 + 64, cur ? Kb0 : Kb1, tid);
    asm volatile("" ::: "memory");

    // in-register softmax (separated phase): mask + exp2 only
#pragma unroll
    for (int mi = 0; mi < 2; ++mi) {
      if constexpr (MASKED) {
        if ((mb32[mi] & fullm) != fullm) {
#pragma unroll
          for (int reg = 0; reg < 4; ++reg)
#pragma unroll
            for (int ni = 0; ni < 4; ++ni)
              if (!((mb32[mi] >> (reg * 8 + ni + hf4)) & 1)) sacc[mi][ni][reg] = -__builtin_inff();
        }
      }
#pragma unroll
      for (int ni = 0; ni < 4; ++ni)
#pragma unroll
        for (int reg = 0; reg < 4; ++reg)
          sacc[mi][ni][reg] = __builtin_amdgcn_exp2f(sacc[mi][ni][reg]);
    }

    // V(t) ready (K(t+1) = newest 2 still in flight when hn)
    if (hn) { asm volatile("s_waitcnt vmcnt(2)" ::: "memory"); }
    else    { asm volatile("s_waitcnt vmcnt(0)" ::: "memory"); }
    __builtin_amdgcn_s_barrier();
    asm volatile("" ::: "memory");

    // O^T += V^T P^T ; l += ones·P^T (row-sum via matrix pipe)
#pragma unroll
    for (int c = 0; c < 2; ++c) {
      half8 bVv[4];
#pragma unroll
      for (int no = 0; no < 4; ++no) {
        const int rV = no * 16 + r16;
        bVv[no] = *reinterpret_cast<const half8*>(
            &Vb[rV * 64 + ((c * 4 + g) ^ (rV & 7)) * 8]);
      }
#pragma unroll
      for (int mi = 0; mi < 2; ++mi) {
        // butterfly P^T frag: target word p_t at lane g <-
        // pk[2c+(g>>1)][p_t&1] of lane 2(g&1)+(p_t>>1)
        int x0 = pkrtz(sacc[mi][2 * c][0],     sacc[mi][2 * c][1]);
        int x1 = pkrtz(sacc[mi][2 * c][2],     sacc[mi][2 * c][3]);
        int x2 = pkrtz(sacc[mi][2 * c + 1][0], sacc[mi][2 * c + 1][1]);
        int x3 = pkrtz(sacc[mi][2 * c + 1][2], sacc[mi][2 * c + 1][3]);
        pl32(x0, x2); pl32(x1, x3);   // resolve g1 <-> ni bit
        pl16(x0, x2); pl16(x1, x3);   // resolve g0 <-> word bit
        int4v wv; wv[0] = x0; wv[1] = x1; wv[2] = x2; wv[3] = x3;
        const half8 aP = __builtin_bit_cast(half8, wv);
        __builtin_amdgcn_s_setprio(1);
#pragma unroll
        for (int no = 0; no < 4; ++no)
          oaccT[mi][no] = __builtin_amdgcn_mfma_f32_16x16x32_f16(bVv[no], aP, oaccT[mi][no], 0, 0, 0);
        lacc4[mi] = __builtin_amdgcn_mfma_f32_16x16x32_f16(vones, aP, lacc4[mi], 0, 0, 0);
        __builtin_amdgcn_s_setprio(0);
      }
    }
    __builtin_amdgcn_s_barrier();
    asm volatile("" ::: "memory");
    // prefetch V(t+1); lands under next tile's QK^T + softmax
    if (hn) stageV64(Vz, s0 + 64, Slen, Vb, tid);
    asm volatile("" ::: "memory");
    cur ^= 1;
  }

  // epilogue: l_q sits in every lane's lacc4[mi][0] (col=lane&15=q).
  // per-wave f32 slab (4KB) lives in the Kb0/Kb1 region (16KB, reads done:
  // all waves passed the post-PV barrier after their last QK/PV reads).
  float ls2[2];
#pragma unroll
  for (int mi = 0; mi < 2; ++mi) ls2[mi] = lacc4[mi][0];

  float* slab = reinterpret_cast<float*>(lds) + w * 1024;
#pragma unroll
  for (int mi = 0; mi < 2; ++mi) {
    const int tq = q0 + w * 32 + mi * 16;
    if (lane < 16) Lp[(long)z * Tc + tq + r16] = ls2[mi];
#pragma unroll
    for (int no = 0; no < 4; ++no) {
      floatx4 v = oaccT[mi][no];
      *reinterpret_cast<floatx4*>(&slab[r16 * 64 + no * 16 + (g ^ (r16 & 3)) * 4]) = v;
    }
#pragma unroll
    for (int it = 0; it < 4; ++it) {
      const int q2 = it * 4 + g;
      const int d4 = r16;
      const floatx4 v = *reinterpret_cast<const floatx4*>(
          &slab[q2 * 64 + (d4 >> 2) * 16 + ((d4 & 3) ^ (q2 & 3)) * 4]);
      const long off = ((long)(b * Tc + tq + q2)) * Cc + h * 64 + d4 * 4;
      half4v hh; hh[0] = (half_t)v[0]; hh[1] = (half_t)v[1];
      hh[2] = (half_t)v[2]; hh[3] = (half_t)v[3];
      // nontemporal: written once, read once by combine (don't evict K/V in L2)
      __builtin_nontemporal_store(__builtin_bit_cast(int2v, hh),
                                  reinterpret_cast<int2v*>(&POh[off]));
    }
  }
}

// 1536 blocks, each exactly 8 s-tiles of 64 (24KB LDS; launch_bounds(256,4)
// keeps natural regalloc — kernel fits 64 VGPR => 6 blocks/CU by LDS):
//  bx < 1024: att0 (chained, masked), s-quarter qt -> slabs 0-3
//  bx >= 1024: att1 (first), s-half sh -> slabs 4-5
__global__ __launch_bounds__(256, 4) void flash_both(
    const half_t* __restrict__ Q2, const half_t* __restrict__ KX,
    const half_t* __restrict__ VXT, const unsigned char* __restrict__ mpk,
    const half_t* __restrict__ QX, const half_t* __restrict__ KY,
    const half_t* __restrict__ VYT,
    half_t* __restrict__ POh, float* __restrict__ Lp)
{
  __shared__ __align__(16) half_t lds[12288];   // 24 KB
  const int bx = blockIdx.x;
  if (bx < 1024) {
    const int z  = ((bx & 7) << 1) | ((bx >> 3) & 1);   // z-local per XCD
    const int qt = (bx >> 4) & 3;
    const int q0 = (bx >> 6) * 128;
    flash_body<true>(Q2, KX, VXT, mpk,
                     POh + (long)qt * BTC, Lp + (long)qt * ZT,
                     Tc, qt * 512, z, q0, lds);
  } else {
    const int b2 = bx - 1024;
    const int z  = ((b2 & 7) << 1) | ((b2 >> 3) & 1);
    const int sh = (b2 >> 4) & 1;
    const int q0 = (b2 >> 5) * 128;
    flash_body<false>(QX, KY, VYT, nullptr,
                      POh + (long)(4 + sh) * BTC, Lp + (long)(4 + sh) * ZT,
                      Mc, sh * 512, z, q0, lds);
  }
}

// --------------------------- combine 6 slabs -> DH  (half8-wide, nt loads)
// DH = (O4+O5)/(l4+l5) - (O0+O1+O2+O3)/(l0+l1+l2+l3)
// 8 consecutive c-elements share (b,t,h) -> one i0/i1 pair per thread.
__global__ __launch_bounds__(256) void combine_k(
    const half_t* __restrict__ POh, const float* __restrict__ Lp,
    half_t* __restrict__ DH)
{
  const long idx = (long)blockIdx.x * 256 + threadIdx.x;   // over BTC/8
  const long c8 = idx * 8;
  const int c = (int)(c8 & (Cc - 1));
  const long bt = c8 >> 9;
  const int h = c >> 6;
  const int b = (int)(bt >> 11), t = (int)(bt & (Tc - 1));
  const long zt = (long)(b * Hc + h) * Tc + t;
  const float i0 = 1.f / (Lp[zt] + Lp[ZT + zt] + Lp[2 * ZT + zt] + Lp[3 * ZT + zt]);
  const float i1 = 1.f / (Lp[4 * ZT + zt] + Lp[5 * ZT + zt]);
  half8 o[6];
#pragma unroll
  for (int s = 0; s < 6; ++s)
    o[s] = __builtin_bit_cast(half8, __builtin_nontemporal_load(
        reinterpret_cast<const int4v*>(POh) + s * (BTC / 8) + idx));
  half8 r;
#pragma unroll
  for (int j = 0; j < 8; ++j) {
    float a0 = 0.f, a1 = 0.f;
#pragma unroll
    for (int s = 0; s < 4; ++s) a0 += (float)o[s][j];
#pragma unroll
    for (int s = 4; s < 6; ++s) a1 += (float)o[s][j];
    r[j] = (half_t)(a1 * i1 - a0 * i0);
  }
  *reinterpret_cast<half8*>(&DH[c8]) = r;
}

// ----------------------------------------------- prep: converts + mask pack
__device__ __forceinline__ void cvt4(const float* in, half_t* out, long i) {
  const float4 f = reinterpret_cast<const float4*>(in)[i];
  half4v h; h[0] = (half_t)f.x; h[1] = (half_t)f.y; h[2] = (half_t)f.z; h[3] = (half_t)f.w;
  reinterpret_cast<half4v*>(out)[i] = h;
}

__global__ __launch_bounds__(256) void prep(
    const float* __restrict__ x, const float* __restrict__ y,
    const float* __restrict__ qw, const float* __restrict__ pw,
    const int* __restrict__ mask,
    half_t* __restrict__ XH, half_t* __restrict__ YH,
    half_t* __restrict__ WQ, half_t* __restrict__ WP,
    unsigned char* __restrict__ mpk)
{
  const long i = (long)blockIdx.x * 256 + threadIdx.x;
  constexpr long n0 = 524288;            // x/4
  constexpr long n1 = n0 + 262144;       // y/4
  constexpr long n2 = n1 + 196608;       // qkv_w/4
  constexpr long n3 = n2 + 65536;        // proj_w/4
  if (i < n0) cvt4(x, XH, i);
  else if (i < n1) cvt4(y, YH, i - n0);
  else if (i < n2) cvt4(qw, WQ, i - n1);
  else if (i < n3) cvt4(pw, WP, i - n2);
  else {
    const long idx = i - n3;             // [0, Tc*256)
    const int t = (int)(idx >> 8), tile = (int)((idx >> 4) & 15), r16 = (int)(idx & 15);
    const int* row = mask + (long)t * Tc + tile * 128 + r16;
    unsigned int bbits = 0;
#pragma unroll
    for (int ni = 0; ni < 8; ++ni)
      bbits |= (row[ni * 16] != 0 ? 1u : 0u) << ni;
    mpk[idx] = (unsigned char)bbits;
  }
}

// ------------------------------------------------------------- workspace map
constexpr size_t OFF_XH   = 0;                                   // [B*T,C] f16 (YH must follow!)
constexpr size_t OFF_YH   = OFF_XH   + (size_t)Bc*Tc*Cc*2;       // contiguous rows after XH
constexpr size_t OFF_WQ   = OFF_YH   + (size_t)Bc*Mc*Cc*2;
constexpr size_t OFF_WP   = OFF_WQ   + (size_t)3*Cc*Cc*2;
constexpr size_t OFF_QX   = OFF_WP   + (size_t)Cc*Cc*2;          // [z,T,D] *0.125*log2e
constexpr size_t OFF_KX   = OFF_QX   + (size_t)Bc*Hc*Tc*Dc*2;    // [z,T,D]
constexpr size_t OFF_VXT  = OFF_KX   + (size_t)Bc*Hc*Tc*Dc*2;    // [z,D,T]
constexpr size_t OFF_QYT  = OFF_VXT  + (size_t)Bc*Hc*Tc*Dc*2;    // [z,D,M] *0.125
constexpr size_t OFF_KY   = OFF_QYT  + (size_t)Bc*Hc*Mc*Dc*2;    // [z,M,D]
constexpr size_t OFF_KYT  = OFF_KY   + (size_t)Bc*Hc*Mc*Dc*2;    // [z,D,M]
constexpr size_t OFF_VYT  = OFF_KYT  + (size_t)Bc*Hc*Mc*Dc*2;    // [z,D,M]
constexpr size_t OFF_Q2   = OFF_VYT  + (size_t)Bc*Hc*Mc*Dc*2;    // [z,T,D]
constexpr size_t OFF_DH   = OFF_Q2   + (size_t)Bc*Hc*Tc*Dc*2;    // [B,T,C] diff f16
constexpr size_t OFF_MPK  = OFF_DH   + (size_t)Bc*Tc*Cc*2;       // [T,16,16] u8
constexpr size_t OFF_PO   = OFF_MPK  + (size_t)Tc*256;           // [6][B,T,C] f16 unnormalized
constexpr size_t OFF_L    = OFF_PO   + (size_t)6*BTC*2;          // [6][ZT] f32 row sums
// total ~65 MB

extern "C" void kernel_launch(void* const* d_in, const int* in_sizes, int n_in,
                              void* d_out, int out_size, void* d_ws, size_t ws_size,
                              hipStream_t stream) {
  const float* x      = (const float*)d_in[0];
  const float* y      = (const float*)d_in[1];
  const int*   mask   = (const int*)  d_in[2];
  const float* qkv_b  = (const float*)d_in[4];
  const float* proj_b = (const float*)d_in[6];
  float* out = (float*)d_out;
  char* ws = (char*)d_ws;

  half_t* XH   = (half_t*)(ws + OFF_XH);
  half_t* YH   = (half_t*)(ws + OFF_YH);
  half_t* WQ   = (half_t*)(ws + OFF_WQ);
  half_t* WP   = (half_t*)(ws + OFF_WP);
  half_t* QX   = (half_t*)(ws + OFF_QX);
  half_t* KX   = (half_t*)(ws + OFF_KX);
  half_t* VXT  = (half_t*)(ws + OFF_VXT);
  half_t* QYT  = (half_t*)(ws + OFF_QYT);
  half_t* KY   = (half_t*)(ws + OFF_KY);
  half_t* KYT  = (half_t*)(ws + OFF_KYT);
  half_t* VYT  = (half_t*)(ws + OFF_VYT);
  half_t* Q2   = (half_t*)(ws + OFF_Q2);
  half_t* DH   = (half_t*)(ws + OFF_DH);
  unsigned char* MPK = (unsigned char*)(ws + OFF_MPK);
  half_t* POh  = (half_t*)(ws + OFF_PO);
  float*  Lp   = (float*) (ws + OFF_L);

  // converts + mask packing (one launch)
  prep<<<6144, 256, 0, stream>>>(x, y, (const float*)d_in[3], (const float*)d_in[5],
                                 mask, XH, YH, WQ, WP, MPK);

  // fused qkv projection for x and y (XH||YH contiguous: 6144 rows)
  {
    EpiParams ep{};
    ep.h0 = QX; ep.h1 = KX; ep.h2 = VXT; ep.h3 = QYT;
    ep.h4 = KY; ep.h5 = KYT; ep.h6 = VYT; ep.bias = qkv_b;
    gemm_nt<128,64,2,2,EPI_QKV_XY,24,48><<<dim3(24, 48, 1), 256, 0, stream>>>(
        XH, WQ, Cc, Cc, Cc, 0, 0, ep);
  }

  // fused WT+Q2: 512 flat blocks (2/CU), XCD remap
  wtq2<<<dim3(512), 256, 0, stream>>>(QYT, KYT, QX, Q2);

  // occupancy-unlocked flash: 1024 att0-quarter + 512 att1-half = 1536
  flash_both<<<dim3(1536), 256, 0, stream>>>(
      Q2, KX, VXT, MPK, QX, KY, VYT, POh, Lp);

  // combine 6 slabs -> DH (half8-wide)
  combine_k<<<(int)(BTC/8/256), 256, 0, stream>>>(POh, Lp, DH);

  // out = DH @ proj_w^T + proj_b  (BN=32: 1024 blocks = 4/CU, XCD remap)
  {
    EpiParams ep{}; ep.f0 = out; ep.bias = proj_b;
    gemm_nt<64,32,2,2,EPI_PROJ,16,64><<<dim3(16, 64, 1), 256, 0, stream>>>(
        DH, WP, Cc, Cc, Cc, 0, 0, ep);
  }
}